// Round 6
// baseline (319.222 us; speedup 1.0000x reference)
//
#include <hip/hip_runtime.h>
#include <cstdint>
#include <cmath>

typedef __bf16 bf16x8 __attribute__((ext_vector_type(8)));
typedef float  f32x4  __attribute__((ext_vector_type(4)));

#define DEVI __device__ __forceinline__

#define SEQ 4096
#define NH 8
#define NKV 4
#define HD 256
#define WIN 1024

DEVI void gload16(const void* g, void* l) {
  __builtin_amdgcn_global_load_lds((const __attribute__((address_space(1))) void*)g,
                                   (__attribute__((address_space(3))) void*)l,
                                   16, 0, 0);
}

DEVI bf16x8 ld8f(const float* p) {
  const f32x4 a = *(const f32x4*)p;
  const f32x4 b = *(const f32x4*)(p + 4);
  bf16x8 r;
#pragma unroll
  for (int j = 0; j < 4; ++j) { r[j] = (__bf16)a[j]; r[4 + j] = (__bf16)b[j]; }
  return r;
}

DEVI void st1(float* p, float v)  { *p = v; }
DEVI void st1(__bf16* p, float v) { *p = (__bf16)v; }

// raw barrier (no vmcnt(0) drain, unlike __syncthreads) + compiler memory fence
DEVI void barx() {
  asm volatile("" ::: "memory");
  __builtin_amdgcn_s_barrier();
  asm volatile("" ::: "memory");
}

// ---------------------------------------------------------------------------
// fp32 -> bf16 conversion. Wq/Wk/Wv concatenated into one 4096x2048 buffer.
// ---------------------------------------------------------------------------
__global__ __launch_bounds__(256)
void cvt_all(const float* __restrict__ x,  const float* __restrict__ wq,
             const float* __restrict__ wk, const float* __restrict__ wv,
             const float* __restrict__ wo,
             __bf16* __restrict__ xb, __bf16* __restrict__ wqkvb,
             __bf16* __restrict__ wob) {
  const size_t g = (size_t)blockIdx.x * 256 + threadIdx.x;
  const float* src; __bf16* dst; size_t off;
  if      (g < 1048576) { src = x;  dst = xb;               off = g; }
  else if (g < 1572864) { src = wq; dst = wqkvb;            off = g - 1048576; }
  else if (g < 1835008) { src = wk; dst = wqkvb + 4194304;  off = g - 1572864; }
  else if (g < 2097152) { src = wv; dst = wqkvb + 6291456;  off = g - 1835008; }
  else                  { src = wo; dst = wob;              off = g - 2097152; }
  *(bf16x8*)(dst + off * 8) = ld8f(src + off * 8);
}

// ---------------------------------------------------------------------------
// GEMM (BM=256 only): m201-style 4-phase fine interleave per K-tile.
// 16 MFMA per barrier amortizes phase overhead — validated rounds 3/4/5.
// ---------------------------------------------------------------------------
template <int BM, typename TC>
__global__ __launch_bounds__(512, 2)
void gemm256(const __bf16* __restrict__ A, const __bf16* __restrict__ B,
             TC* __restrict__ C, int N, int K) {
  constexpr int AI    = BM / 128;
  constexpr int MF    = BM / 32;
  constexpr int MH    = MF / 2;
  constexpr int AUNIT = BM * 64;
  constexpr int ASZ   = 4 * AUNIT;
  constexpr int VMC   = 2 * AI + 4;
  __shared__ char lds[ASZ + 65536];

  const int tid  = threadIdx.x;
  const int lane = tid & 63;
  const int wave = tid >> 6;
  const int l15  = lane & 15;
  const int l4   = lane >> 4;
  const int wm   = wave >> 2;
  const int wn   = wave & 3;

  constexpr int nTm = 4096 / BM;
  const int lin  = blockIdx.x;
  const int xcd  = lin & 7;
  const int kk   = lin >> 3;
  const int nTn  = N >> 8;
  const int rowT = kk % nTm;
  const int colT = xcd * (nTn >> 3) + kk / nTm;
  const int row0 = rowT * BM;
  const int col0 = colT << 8;

  const int srow = tid >> 2;
  const int scol = ((tid & 3) ^ ((tid >> 3) & 3)) << 3;
  const __bf16* Asrc = A + (size_t)(row0 + srow) * K + scol;
  const __bf16* Bsrc = B + (size_t)(col0 + srow) * K + scol;

  const int swz  = (l4 ^ ((l15 >> 1) & 3)) << 4;
  const int aoff = (wm * (BM / 2) + l15) * 64 + swz;
  const int boff = ((wn << 6) + l15) * 64 + swz;

  auto stA = [&](int kx, int h) {
    int k0 = kx << 6; if (k0 >= K) k0 = 0;
    const __bf16* s = Asrc + k0 + (h << 5);
    char* d = lds + ((kx & 1) * 2 + h) * AUNIT + wave * 1024;
#pragma unroll
    for (int i = 0; i < AI; ++i)
      gload16(s + (size_t)(i << 7) * K, d + i * 8192);
  };
  auto stB = [&](int kx, int h) {
    int k0 = kx << 6; if (k0 >= K) k0 = 0;
    const __bf16* s = Bsrc + k0 + (h << 5);
    char* d = lds + ASZ + ((kx & 1) * 2 + h) * 16384 + wave * 1024;
#pragma unroll
    for (int i = 0; i < 2; ++i)
      gload16(s + (size_t)(i << 7) * K, d + i * 8192);
  };

  f32x4 acc[MF][4] = {};

  stA(0, 0); stB(0, 0); stA(0, 1); stB(0, 1); stA(1, 0); stB(1, 0);
  asm volatile("s_waitcnt vmcnt(%0)" :: "i"(VMC) : "memory");
  barx();

  const int NT = K >> 6;
  for (int kt = 0; kt < NT; ++kt) {
    const int bb = (kt & 1) * 2;
    bf16x8 bfr[4];
    bf16x8 af[MH];

    auto rd = [&](int h, int mg, bool readB) {
      const char* pa = lds + (bb + h) * AUNIT + aoff;
#pragma unroll
      for (int m = 0; m < MH; ++m)
        af[m] = *(const bf16x8*)(pa + ((mg * MH + m) << 10));
      if (readB) {
        const char* pb = lds + ASZ + (bb + h) * 16384 + boff;
#pragma unroll
        for (int n = 0; n < 4; ++n)
          bfr[n] = *(const bf16x8*)(pb + (n << 10));
      }
    };
    auto mm = [&](int mg) {
      barx();
      __builtin_amdgcn_s_setprio(1);
#pragma unroll
      for (int m = 0; m < MH; ++m)
#pragma unroll
        for (int n = 0; n < 4; ++n)
          acc[mg * MH + m][n] =
              __builtin_amdgcn_mfma_f32_16x16x32_bf16(af[m], bfr[n], acc[mg * MH + m][n], 0, 0, 0);
      __builtin_amdgcn_s_setprio(0);
    };

    // p0
    rd(0, 0, true);
    stA(kt + 1, 1);
    mm(0);
    // p1
    rd(0, 1, false);
    stB(kt + 1, 1);
    asm volatile("s_waitcnt vmcnt(%0)" :: "i"(VMC) : "memory");
    mm(1);
    // p2
    rd(1, 0, true);
    stA(kt + 2, 0);
    mm(0);
    // p3
    rd(1, 1, false);
    stB(kt + 2, 0);
    asm volatile("s_waitcnt vmcnt(%0)" :: "i"(VMC) : "memory");
    mm(1);
  }
  asm volatile("s_waitcnt vmcnt(0)" ::: "memory");

#pragma unroll
  for (int mf = 0; mf < MF; ++mf) {
    const int rb = row0 + wm * (BM / 2) + (mf >> 2) * 64 + (mf & 3) * 16 + (l4 << 2);
#pragma unroll
    for (int reg = 0; reg < 4; ++reg) {
      TC* crow = C + (size_t)(rb + reg) * N + col0 + (wn << 6) + l15;
#pragma unroll
      for (int n = 0; n < 4; ++n) st1(crow + (n << 4), acc[mf][n][reg]);
    }
  }
}

// ---------------------------------------------------------------------------
// gemmOP: out-projection GEMM. 128x128 tile, 256 threads (4 waves = 2M x 2N),
// 64 KB LDS -> 2 blocks/CU: restores inter-block latency hiding (m114) that
// the 512-thr/98KB gemm2ph<128> lacked (1 block/CU -> every gate/barrier was
// a whole-CU stall). Proven 2-phase schedule: per half-phase {vmcnt(8) gate,
// barrier, 8 ds_read_b128, stage A+B unit (4 gload_lds), 16 MFMA}.
//   unit = 128 rows x 32 cols bf16 = 8 KB = 2 issues x (256thr x 16B).
//   VMC = 8 = 2 stage-groups in flight (same derivation as r1; the slot read
//   at half h was staged 2 halves earlier, exactly 2 groups of 4 issued
//   after it). Tail = clamped dummy re-issues; exit vmcnt(0).
//   M fixed 4096 (nTm=32); XCD swizzle: per-XCD column band (1 MB, L2-fit).
// ---------------------------------------------------------------------------
template <typename TC>
__global__ __launch_bounds__(256, 2)
void gemmOP(const __bf16* __restrict__ A, const __bf16* __restrict__ B,
            TC* __restrict__ C, int N, int K) {
  __shared__ char lds[65536];          // A: 4 units x 8KB, B: 4 units x 8KB

  const int tid  = threadIdx.x;
  const int lane = tid & 63;
  const int wave = tid >> 6;           // 0..3
  const int l15  = lane & 15;
  const int l4   = lane >> 4;
  const int wm   = wave >> 1;          // 0..1
  const int wn   = wave & 1;           // 0..1

  constexpr int nTm = 32;              // M = 4096 fixed
  const int nTn  = N >> 7;
  const int cpx  = nTn >> 3;           // col-tiles per XCD
  const int lin  = blockIdx.x;
  const int xcd  = lin & 7;
  const int kk   = lin >> 3;           // 0..nTm*cpx-1
  const int rowT = kk % nTm;
  const int colT = xcd * cpx + kk / nTm;
  const int row0 = rowT << 7;
  const int col0 = colT << 7;

  // staging: linear LDS dest; source col16 pre-swizzled (involution).
  // unit layout: [128 rows][32 bf16]; issue i covers rows i*64 + tid/4.
  const int srow = tid >> 2;
  const int scol = ((tid & 3) ^ ((tid >> 3) & 3)) << 3;
  const __bf16* Asrc = A + (size_t)(row0 + srow) * K + scol;
  const __bf16* Bsrc = B + (size_t)(col0 + srow) * K + scol;

  const int swz  = (l4 ^ ((l15 >> 1) & 3)) << 4;
  const int aoff = ((wm << 6) + l15) * 64 + swz;
  const int boff = ((wn << 6) + l15) * 64 + swz;

  auto stA = [&](int kx, int h, int b) {
    int k0 = kx << 6; if (k0 >= K) k0 = 0;        // tail: clamped dummy
    const __bf16* s = Asrc + k0 + (h << 5);
    char* d = lds + (b * 2 + h) * 8192 + tid * 16;
#pragma unroll
    for (int i = 0; i < 2; ++i)
      gload16(s + (size_t)(i << 6) * K, d + i * 4096);
  };
  auto stB = [&](int kx, int h, int b) {
    int k0 = kx << 6; if (k0 >= K) k0 = 0;
    const __bf16* s = Bsrc + k0 + (h << 5);
    char* d = lds + 32768 + (b * 2 + h) * 8192 + tid * 16;
#pragma unroll
    for (int i = 0; i < 2; ++i)
      gload16(s + (size_t)(i << 6) * K, d + i * 4096);
  };

  f32x4 acc[4][4] = {};

  // prologue: 3 stage-groups in steady-state order
  stA(0, 0, 0); stB(0, 0, 0);
  stA(0, 1, 0); stB(0, 1, 0);
  stA(1, 0, 1); stB(1, 0, 1);

  const int NT = K >> 6;
  for (int kt = 0; kt < NT; ++kt) {
    const int b = kt & 1, nb = b ^ 1;
#pragma unroll
    for (int half = 0; half < 2; ++half) {
      asm volatile("s_waitcnt vmcnt(8)" ::: "memory");
      barx();
      bf16x8 af[4], bfr[4];
      const char* pa = lds + (b * 2 + half) * 8192 + aoff;
      const char* pb = lds + 32768 + (b * 2 + half) * 8192 + boff;
#pragma unroll
      for (int m = 0; m < 4; ++m) af[m] = *(const bf16x8*)(pa + (m << 10));
#pragma unroll
      for (int n = 0; n < 4; ++n) bfr[n] = *(const bf16x8*)(pb + (n << 10));
      // prefetch (after this phase's barrier => targets retired)
      if (half == 0) { stA(kt + 1, 1, nb); stB(kt + 1, 1, nb); }
      else           { stA(kt + 2, 0, b);  stB(kt + 2, 0, b);  }
      __builtin_amdgcn_s_setprio(1);
#pragma unroll
      for (int m = 0; m < 4; ++m)
#pragma unroll
        for (int n = 0; n < 4; ++n)
          acc[m][n] = __builtin_amdgcn_mfma_f32_16x16x32_bf16(af[m], bfr[n], acc[m][n], 0, 0, 0);
      __builtin_amdgcn_s_setprio(0);
    }
  }
  asm volatile("s_waitcnt vmcnt(0)" ::: "memory");

  // C/D layout: col = lane&15, row = (lane>>4)*4 + reg
#pragma unroll
  for (int mf = 0; mf < 4; ++mf) {
    const int rb = row0 + (wm << 6) + mf * 16 + (l4 << 2);
#pragma unroll
    for (int reg = 0; reg < 4; ++reg) {
      TC* crow = C + (size_t)(rb + reg) * N + col0 + (wn << 6) + l15;
#pragma unroll
      for (int n = 0; n < 4; ++n) st1(crow + (n << 4), acc[mf][n][reg]);
    }
  }
}

// ---------------------------------------------------------------------------
// Merged: per-head RMSNorm+RoPE (blocks 0..12287) and V-transpose (12288+).
// ---------------------------------------------------------------------------
__global__ __launch_bounds__(256)
void norm_rope_tv(__bf16* __restrict__ qkv, __bf16* __restrict__ Vt,
                  const float* __restrict__ qw, const float* __restrict__ kw,
                  const int* __restrict__ pos) {
  if (blockIdx.x < 12288) {
    const int gw   = blockIdx.x * 4 + (threadIdx.x >> 6);
    const int lane = threadIdx.x & 63;
    __bf16* base; const float* w; int t;
    if (gw < SEQ * NH) {
      t = gw >> 3;
      base = qkv + (size_t)t * 4096 + (gw & 7) * HD;
      w = qw;
    } else {
      const int g = gw - SEQ * NH;
      t = g >> 2;
      base = qkv + (size_t)t * 4096 + 2048 + (g & 3) * HD;
      w = kw;
    }

    const int d0 = lane * 4;
    float v[4]; float ss = 0.f;
#pragma unroll
    for (int j = 0; j < 4; ++j) { v[j] = (float)base[d0 + j]; ss += v[j] * v[j]; }
#pragma unroll
    for (int off = 1; off < 64; off <<= 1) ss += __shfl_xor(ss, off);
    const float rms = rsqrtf(ss * (1.0f / 256.0f) + 1e-6f);
    const float p = (float)pos[t];

    float n[4];
#pragma unroll
    for (int j = 0; j < 4; ++j) n[j] = v[j] * rms * w[d0 + j];

    float outv[4];
#pragma unroll
    for (int e = 0; e < 4; e += 2) {
      const int i0 = d0 + e, i1 = i0 + 1;
      const float f0 = exp2f(-(float)(i0 & 127) * 0.103810253f);
      const float f1 = exp2f(-(float)(i1 & 127) * 0.103810253f);
      float s0, cc0, s1, cc1;
      sincosf(p * f0, &s0, &cc0);
      sincosf(p * f1, &s1, &cc1);
      outv[e]     = n[e] * cc0 - n[e + 1] * s0;
      outv[e + 1] = n[e + 1] * cc1 + n[e] * s1;
    }
#pragma unroll
    for (int j = 0; j < 4; ++j) base[d0 + j] = (__bf16)outv[j];
  } else {
    __shared__ __bf16 tile[64][72];
    const int b   = blockIdx.x - 12288;       // 0..1023
    const int tid = threadIdx.x;
    const int tb  = (b & 63) * 64;
    const int yy  = b >> 6;                   // 0..15
    const int kvh = yy >> 2;
    const int db  = (yy & 3) * 64;
#pragma unroll
    for (int i = 0; i < 2; ++i) {
      const int s = i * 256 + tid;
      const int r = s >> 3, c = (s & 7) * 8;
      bf16x8 val = *(const bf16x8*)(qkv + (size_t)(tb + r) * 4096 + 3072 + kvh * HD + db + c);
#pragma unroll
      for (int j = 0; j < 8; ++j) tile[r][c + j] = val[j];
    }
    __syncthreads();
#pragma unroll
    for (int i = 0; i < 2; ++i) {
      const int s = i * 256 + tid;
      const int r = s >> 3, c = (s & 7) * 8;
      bf16x8 outv;
#pragma unroll
      for (int j = 0; j < 8; ++j) outv[j] = tile[c + j][r];
      *(bf16x8*)(Vt + (size_t)(kvh * HD + db + r) * SEQ + tb + c) = outv;
    }
  }
}

// ---------------------------------------------------------------------------
// Sliding-window flash attention — v2 structure + wave-uniform full-tile
// softmax fast path (validated round 5: dropped out of top-5).
// ---------------------------------------------------------------------------
__global__ __launch_bounds__(256, 2)
void attn_fwd(const __bf16* __restrict__ qkv, const __bf16* __restrict__ Vt,
              __bf16* __restrict__ Y) {
  __shared__ char klds[2][16384];      // [slot][32 key][32 dim] rows of 64B, swz
  __shared__ char vlds[2][16384];      // [slot][256 dim][32 key] rows of 64B, swz
  __shared__ __bf16 Ps[4][16][40];     // per-wave P (padded rows)
  const int tid  = threadIdx.x;
  const int lane = tid & 63;
  const int wave = tid >> 6;
  const int l15  = lane & 15;
  const int l4   = lane >> 4;
  const int lin  = blockIdx.x;
  const int head = lin & 7;            // head-per-XCD pinning
  const int q0   = (lin >> 3) * 64;
  const int kvh  = head >> 1;
  const int qw   = q0 + wave * 16;

  // Q fragments: A[m=lane&15][k=(lane>>4)*8+j]; pre-scale 1/16 (exact pow2)
  bf16x8 qf[8];
  const __bf16* qrow = qkv + (size_t)(qw + l15) * 4096 + head * HD;
#pragma unroll
  for (int ks = 0; ks < 8; ++ks) {
    bf16x8 t = *(const bf16x8*)(qrow + ks * 32 + l4 * 8);
#pragma unroll
    for (int j = 0; j < 8; ++j) t[j] = (__bf16)((float)t[j] * 0.0625f);
    qf[ks] = t;
  }

  f32x4 o[16] = {};
  float l_run[4] = {0.f, 0.f, 0.f, 0.f};

  int lo = q0 - (WIN - 1); if (lo < 0) lo = 0;
  const int kt0 = lo >> 5;
  const int kt1 = (q0 + 63) >> 5;      // >= kt0+1 always (>=2 tiles)
  const int kbmax = kt1 << 5;

  const int skey = (tid >> 2) & 31;                 // K: key row
  const int sdim = tid >> 2;                        // V: dim row (+ i*64)
  const int sg   = (tid & 3) ^ ((tid >> 3) & 3);    // swizzled source col16
  const int sth  = tid >> 7;

  auto stK = [&](int kt, int b) {
    int kb = kt << 5; if (kb > kbmax) kb = kbmax;   // clamped dummy re-issue
    const __bf16* s = qkv + (size_t)(kb + skey) * 4096 + 2048 + kvh * HD
                          + sth * 32 + sg * 8;
    char* d = klds[b] + wave * 1024;
#pragma unroll
    for (int i = 0; i < 4; ++i)
      gload16(s + i * 64, d + i * 4096);
  };
  auto stV = [&](int kt, int b) {
    int kb = kt << 5; if (kb > kbmax) kb = kbmax;
    const __bf16* s = Vt + ((size_t)kvh * HD + sdim) * SEQ + kb + sg * 8;
    char* d = vlds[b] + wave * 1024;
#pragma unroll
    for (int i = 0; i < 4; ++i)
      gload16(s + (size_t)i * 64 * SEQ, d + i * 4096);
  };

  stK(kt0, 0);     stV(kt0, 0);
  stK(kt0 + 1, 1); stV(kt0 + 1, 1);

  const int rswz = (l4 ^ ((l15 >> 1) & 3)) << 4;

  for (int kt = kt0; kt <= kt1; ++kt) {
    const int p  = (kt - kt0) & 1;
    const int kb = kt << 5;
    asm volatile("s_waitcnt vmcnt(8)" ::: "memory");
    barx();

    // S = (Q/16) K^T   (32 keys: kn = 0..1)
    const char* kbase = klds[p];
    f32x4 s_acc[2] = {};
    __builtin_amdgcn_s_setprio(1);
#pragma unroll
    for (int kn = 0; kn < 2; ++kn) {
#pragma unroll
      for (int ks = 0; ks < 8; ++ks) {
        bf16x8 kf = *(const bf16x8*)(kbase + (ks * 32 + kn * 16 + l15) * 64 + rswz);
        s_acc[kn] = __builtin_amdgcn_mfma_f32_16x16x32_bf16(qf[ks], kf, s_acc[kn], 0, 0, 0);
      }
    }
    __builtin_amdgcn_s_setprio(0);

    // fixed-max softmax: p = exp(min(s,34)-34); masked -> 0
    // Fast path (wave-uniform): tile fully inside causal+window for all 16
    // rows of this wave iff kb+31 <= qw  &&  kb >= qw-1008.
    if ((kb + 31 <= qw) && (kb >= qw - 1008)) {
#pragma unroll
      for (int reg = 0; reg < 4; ++reg) {
        const int r = l4 * 4 + reg;
        float ps = 0.f;
#pragma unroll
        for (int kn = 0; kn < 2; ++kn) {
          const float pv = __expf(fminf(s_acc[kn][reg], 34.f) - 34.f);
          ps += pv;
          Ps[wave][r][kn * 16 + l15] = (__bf16)pv;
        }
        l_run[reg] += ps;
      }
    } else {
#pragma unroll
      for (int reg = 0; reg < 4; ++reg) {
        const int r  = l4 * 4 + reg;
        const int qg = qw + r;
        float ps = 0.f;
#pragma unroll
        for (int kn = 0; kn < 2; ++kn) {
          const int kg = kb + kn * 16 + l15;
          const bool ok = (kg <= qg) && (kg > qg - WIN);
          const float pv = ok ? __expf(fminf(s_acc[kn][reg], 34.f) - 34.f) : 0.f;
          ps += pv;
          Ps[wave][r][kn * 16 + l15] = (__bf16)pv;
        }
        l_run[reg] += ps;
      }
    }

    // O += P V   (Ps per-wave; intra-wave LDS ordering needs no barrier)
    const char* vbase = vlds[p];
    bf16x8 pf = *(const bf16x8*)&Ps[wave][l15][l4 * 8];
    __builtin_amdgcn_s_setprio(1);
#pragma unroll
    for (int dn = 0; dn < 16; ++dn) {
      bf16x8 vf = *(const bf16x8*)(vbase + (dn * 16 + l15) * 64 + rswz);
      o[dn] = __builtin_amdgcn_mfma_f32_16x16x32_bf16(pf, vf, o[dn], 0, 0, 0);
    }
    __builtin_amdgcn_s_setprio(0);

    // retire buf p readers, then refill it with tile kt+2
    barx();
    stK(kt + 2, p);
    stV(kt + 2, p);
  }
  // no DMA in flight at exit (LDS may be reassigned to the next block)
  asm volatile("s_waitcnt vmcnt(0)" ::: "memory");

  // epilogue: reduce l across the 16 lanes sharing each row, then scale
#pragma unroll
  for (int reg = 0; reg < 4; ++reg) {
#pragma unroll
    for (int off = 1; off < 16; off <<= 1)
      l_run[reg] += __shfl_xor(l_run[reg], off);
    const float inv = 1.0f / l_run[reg];
    const int q = qw + l4 * 4 + reg;
    __bf16* yrow = Y + ((size_t)q * NH + head) * HD + l15;
#pragma unroll
    for (int dn = 0; dn < 16; ++dn)
      yrow[dn * 16] = (__bf16)(o[dn][reg] * inv);
  }
}

// ---------------------------------------------------------------------------
extern "C" void kernel_launch(void* const* d_in, const int* in_sizes, int n_in,
                              void* d_out, int out_size, void* d_ws, size_t ws_size,
                              hipStream_t stream) {
  (void)in_sizes; (void)n_in; (void)out_size; (void)ws_size;
  const float* x   = (const float*)d_in[0];
  const int*   pos = (const int*)d_in[1];
  const float* Wq  = (const float*)d_in[2];
  const float* Wk  = (const float*)d_in[3];
  const float* Wv  = (const float*)d_in[4];
  const float* Wo  = (const float*)d_in[5];
  const float* qw  = (const float*)d_in[6];
  const float* kw  = (const float*)d_in[7];
  float* out = (float*)d_out;

  char* ws = (char*)d_ws;
  const size_t MB = 1024 * 1024;
  __bf16* qkv_ws = (__bf16*)(ws);             // 32 MiB  [4096][4096]
  __bf16* vt_ws  = (__bf16*)(ws + 32 * MB);   //  8 MiB  [4][256][4096]
  __bf16* y_ws   = (__bf16*)(ws + 40 * MB);   // 16 MiB  [4096][2048]
  __bf16* xb     = (__bf16*)(ws + 56 * MB);   // 16 MiB
  __bf16* wqkvb  = (__bf16*)(ws + 72 * MB);   // 16 MiB  [4096][2048]
  __bf16* wob    = (__bf16*)(ws + 88 * MB);   //  8 MiB  (total 96 MiB)

  cvt_all<<<dim3(10240), dim3(256), 0, stream>>>(x, Wq, Wk, Wv, Wo, xb, wqkvb, wob);
  gemm256<256, __bf16><<<dim3(256), dim3(512), 0, stream>>>(xb, wqkvb, qkv_ws, 4096, 2048);
  norm_rope_tv<<<dim3(13312), dim3(256), 0, stream>>>(qkv_ws, vt_ws, qw, kw, pos);
  attn_fwd<<<dim3(512), dim3(256), 0, stream>>>(qkv_ws, vt_ws, y_ws);
  gemmOP<float><<<dim3(512), dim3(256), 0, stream>>>(y_ws, wob, out, 2048, 2048);
}